// Round 2
// baseline (1709.916 us; speedup 1.0000x reference)
//
#include <hip/hip_runtime.h>
#include <hip/hip_bf16.h>

typedef __bf16 bf16;
typedef __bf16 bf16x8 __attribute__((ext_vector_type(8)));
typedef float  f32x4  __attribute__((ext_vector_type(4)));
typedef float  f32x16 __attribute__((ext_vector_type(16)));

#define BATCH   16384
#define VOCAB   100000
#define NSPARSE 26

#define GLOBAL_AS __attribute__((address_space(1)))
#define LDS_AS    __attribute__((address_space(3)))

__device__ __forceinline__ void async_copy16(const bf16* g, bf16* l) {
    __builtin_amdgcn_global_load_lds((const GLOBAL_AS void*)g, (LDS_AS void*)l, 16, 0, 0);
}

// ---------------------------------------------------------------------------
// Weight transpose+convert: w[K][N] fp32 -> wt[N][Kpad] bf16, zero-pad k>=K
// ---------------------------------------------------------------------------
__global__ void transpose_w_kernel(const float* __restrict__ w, bf16* __restrict__ wt,
                                   int K, int N, int Kpad) {
    int i = blockIdx.x * 256 + threadIdx.x;
    if (i >= N * Kpad) return;
    int n = i / Kpad;
    int k = i - n * Kpad;
    wt[i] = (k < K) ? (bf16)w[(size_t)k * N + n] : (bf16)0.f;
}

// ---------------------------------------------------------------------------
// Bottom layer 0: h0 = relu(dense @ bw0 + bb0), dense 16384x13 fp32, bw0 13x512
// fp32 compute (K=13, trivial), bf16 output. Block=256 threads -> 8 rows.
// ---------------------------------------------------------------------------
__global__ __launch_bounds__(256) void bot0_kernel(const float* __restrict__ dense,
                                                   const float* __restrict__ w,
                                                   const float* __restrict__ b,
                                                   bf16* __restrict__ h0) {
    __shared__ float ws_[13 * 512];
    __shared__ float ds_[8 * 13];
    int t  = threadIdx.x;
    int r0 = blockIdx.x * 8;
    for (int i = t; i < 13 * 512; i += 256) ws_[i] = w[i];
    for (int i = t; i < 8 * 13;   i += 256) ds_[i] = dense[(size_t)r0 * 13 + i];
    __syncthreads();
    float acc[8][2];
    for (int r = 0; r < 8; r++) { acc[r][0] = 0.f; acc[r][1] = 0.f; }
    for (int k = 0; k < 13; k++) {
        float w0 = ws_[k * 512 + t];
        float w1 = ws_[k * 512 + t + 256];
        for (int r = 0; r < 8; r++) {
            float d = ds_[r * 13 + k];
            acc[r][0] += d * w0;
            acc[r][1] += d * w1;
        }
    }
    float b0 = b[t], b1 = b[t + 256];
    for (int r = 0; r < 8; r++) {
        h0[(size_t)(r0 + r) * 512 + t]       = (bf16)fmaxf(acc[r][0] + b0, 0.f);
        h0[(size_t)(r0 + r) * 512 + t + 256] = (bf16)fmaxf(acc[r][1] + b1, 0.f);
    }
}

// ---------------------------------------------------------------------------
// Generic MFMA GEMM: C[M][N] = act(A[M][K] @ W + bias), W given as Wt[N][K] bf16.
// 128x128 tile, BK=32, 256 threads = 4 waves (2x2 of 64x64), mfma 16x16x32 bf16.
// M,N multiples of 128; K multiple of 32. A,C bf16; bias fp32.
// ---------------------------------------------------------------------------
__global__ __launch_bounds__(256) void gemm_kernel(const bf16* __restrict__ A,
                                                   const bf16* __restrict__ Wt,
                                                   const float* __restrict__ bias,
                                                   bf16* __restrict__ C,
                                                   int M, int N, int K, int do_relu) {
    __shared__ bf16 As[128 * 32];
    __shared__ bf16 Ws[128 * 32];
    const int t    = threadIdx.x;
    const int wave = t >> 6;
    const int lane = t & 63;
    const int m0   = blockIdx.x * 128;
    const int n0   = blockIdx.y * 128;
    const int wm   = (wave & 1) * 64;
    const int wn   = (wave >> 1) * 64;
    const int q    = lane >> 4;   // quad 0..3
    const int l16  = lane & 15;

    // staging: thread t loads 16B (8 bf16); per-wave LDS dest = base + lane*16
    const int srow = t >> 2;            // 0..63
    const int scol = (t & 3) * 8;       // 0,8,16,24
    const bf16* ag = A  + (size_t)(m0 + srow) * K + scol;
    const bf16* wg = Wt + (size_t)(n0 + srow) * K + scol;
    const size_t rowK64 = (size_t)64 * K;
    bf16* lA0 = &As[srow * 32 + scol];
    bf16* lA1 = &As[(64 + srow) * 32 + scol];
    bf16* lW0 = &Ws[srow * 32 + scol];
    bf16* lW1 = &Ws[(64 + srow) * 32 + scol];

    f32x4 acc[4][4];
    for (int mi = 0; mi < 4; mi++)
        for (int ni = 0; ni < 4; ni++)
            for (int r = 0; r < 4; r++) acc[mi][ni][r] = 0.f;

    for (int bk = 0; bk < K; bk += 32) {
        async_copy16(ag + bk,          lA0);
        async_copy16(ag + bk + rowK64, lA1);
        async_copy16(wg + bk,          lW0);
        async_copy16(wg + bk + rowK64, lW1);
        __syncthreads();
        bf16x8 af[4], bfr[4];
        for (int i = 0; i < 4; i++)
            af[i]  = *(const bf16x8*)&As[(wm + i * 16 + l16) * 32 + q * 8];
        for (int i = 0; i < 4; i++)
            bfr[i] = *(const bf16x8*)&Ws[(wn + i * 16 + l16) * 32 + q * 8];
        for (int mi = 0; mi < 4; mi++)
            for (int ni = 0; ni < 4; ni++)
                acc[mi][ni] = __builtin_amdgcn_mfma_f32_16x16x32_bf16(
                    af[mi], bfr[ni], acc[mi][ni], 0, 0, 0);
        __syncthreads();
    }

    // epilogue: C/D map for 16x16: col = lane&15, row = (lane>>4)*4 + reg
    for (int ni = 0; ni < 4; ni++) {
        int gn = n0 + wn + ni * 16 + l16;
        float bv = bias[gn];
        for (int mi = 0; mi < 4; mi++) {
            int gm = m0 + wm + mi * 16 + q * 4;
            for (int r = 0; r < 4; r++) {
                float v = acc[mi][ni][r] + bv;
                if (do_relu) v = fmaxf(v, 0.f);
                C[(size_t)(gm + r) * N + gn] = (bf16)v;
            }
        }
    }
}

// ---------------------------------------------------------------------------
// Interaction: one wave per sample. F = [bot_out; emb rows] (27x128, pad to 32).
// D = F F^T via mfma_f32_32x32x16_bf16 with identical A/B frags (8 k-chunks).
// emb is fp32 (gathered + converted in-register); bot is bf16.
// Writes top_in[s][0:128]=bot_out, [128:506]=triu(D), [506:512]=0.  (bf16)
// ---------------------------------------------------------------------------
__global__ __launch_bounds__(256) void interact_kernel(const int* __restrict__ cat,
                                                       const float* __restrict__ emb,
                                                       const bf16* __restrict__ bot,
                                                       bf16* __restrict__ top_in) {
    int wave = threadIdx.x >> 6;
    int lane = threadIdx.x & 63;
    int s = blockIdx.x * 4 + wave;
    int m = lane & 31;      // F-row this lane owns
    int h = lane >> 5;      // k-half

    const float* erow = nullptr;
    if (m >= 1 && m <= NSPARSE) {
        int idx = cat[(size_t)s * NSPARSE + (m - 1)] + (m - 1) * VOCAB;
        erow = emb + (size_t)idx * 128;
    }
    const bf16* botp = bot + (size_t)s * 128;

    f32x16 acc;
    for (int r = 0; r < 16; r++) acc[r] = 0.f;

    for (int ck = 0; ck < 8; ck++) {
        bf16x8 frag;
        if (m == 0) {
            frag = *(const bf16x8*)(botp + ck * 16 + h * 8);
        } else if (erow) {
            const float* rp = erow + ck * 16 + h * 8;
            for (int j = 0; j < 8; j++) frag[j] = (bf16)rp[j];
        } else {
            for (int j = 0; j < 8; j++) frag[j] = (bf16)0.f;
        }
        acc = __builtin_amdgcn_mfma_f32_32x32x16_bf16(frag, frag, acc, 0, 0, 0);
    }

    bf16* tp = top_in + (size_t)s * 512;
    // cols 0..127 = bot_out (64 lanes x 4B)
    ((unsigned int*)tp)[lane] = ((const unsigned int*)botp)[lane];
    // zero pad cols 506..511
    if (lane < 3) ((unsigned int*)tp)[253 + lane] = 0u;
    // triu scatter; C/D map 32x32: col=lane&31, row=(reg&3)+8*(reg>>2)+4*(lane>>5)
    for (int r = 0; r < 16; r++) {
        int row = (r & 3) + 8 * (r >> 2) + 4 * h;
        int col = m;
        if (row <= col && col <= NSPARSE) {
            int tpos = row * 27 - (row * (row - 1)) / 2 + (col - row);
            tp[128 + tpos] = (bf16)acc[r];
        }
    }
}

// ---------------------------------------------------------------------------
// Final layer: out[s] = h[s][0:256] . w + b   (no relu). One wave per row.
// h bf16, w/b fp32, out fp32.
// ---------------------------------------------------------------------------
__global__ __launch_bounds__(256) void out_kernel(const bf16* __restrict__ h,
                                                  const float* __restrict__ w,
                                                  const float* __restrict__ b,
                                                  float* __restrict__ out) {
    int wave = threadIdx.x >> 6;
    int lane = threadIdx.x & 63;
    int s = blockIdx.x * 4 + wave;
    const bf16* hp = h + (size_t)s * 256;
    float sum = 0.f;
    for (int j = 0; j < 4; j++)
        sum += (float)hp[lane * 4 + j] * w[lane * 4 + j];
    for (int off = 32; off > 0; off >>= 1)
        sum += __shfl_down(sum, off, 64);
    if (lane == 0) out[s] = sum + b[0];
}

// ---------------------------------------------------------------------------
extern "C" void kernel_launch(void* const* d_in, const int* in_sizes, int n_in,
                              void* d_out, int out_size, void* d_ws, size_t ws_size,
                              hipStream_t stream) {
    const float* dense = (const float*)d_in[0];
    const int*   cat   = (const int*)d_in[1];
    const float* emb   = (const float*)d_in[2];
    const float* bw0   = (const float*)d_in[3];
    const float* bb0   = (const float*)d_in[4];
    const float* bw1   = (const float*)d_in[5];
    const float* bb1   = (const float*)d_in[6];
    const float* bw2   = (const float*)d_in[7];
    const float* bb2   = (const float*)d_in[8];
    const float* tw0   = (const float*)d_in[9];
    const float* tb0   = (const float*)d_in[10];
    const float* tw1   = (const float*)d_in[11];
    const float* tb1   = (const float*)d_in[12];
    const float* tw2   = (const float*)d_in[13];
    const float* tb2   = (const float*)d_in[14];
    const float* tw3   = (const float*)d_in[15];
    const float* tb3   = (const float*)d_in[16];
    const float* tw4   = (const float*)d_in[17];
    const float* tb4   = (const float*)d_in[18];
    float* out = (float*)d_out;

    char* ws = (char*)d_ws;
    bf16* bufA = (bf16*)ws;  ws += (size_t)BATCH * 1024 * sizeof(bf16);
    bf16* bufB = (bf16*)ws;  ws += (size_t)BATCH * 1024 * sizeof(bf16);
    bf16* wtb1 = (bf16*)ws;  ws += (size_t)256  * 512  * sizeof(bf16);
    bf16* wtb2 = (bf16*)ws;  ws += (size_t)128  * 256  * sizeof(bf16);
    bf16* wtt0 = (bf16*)ws;  ws += (size_t)1024 * 512  * sizeof(bf16);
    bf16* wtt1 = (bf16*)ws;  ws += (size_t)1024 * 1024 * sizeof(bf16);
    bf16* wtt2 = (bf16*)ws;  ws += (size_t)512  * 1024 * sizeof(bf16);
    bf16* wtt3 = (bf16*)ws;  ws += (size_t)256  * 512  * sizeof(bf16);

    // weight transposes+convert (K, N, Kpad)
    transpose_w_kernel<<<(256 * 512 + 255) / 256, 256, 0, stream>>>(bw1, wtb1, 512, 256, 512);
    transpose_w_kernel<<<(128 * 256 + 255) / 256, 256, 0, stream>>>(bw2, wtb2, 256, 128, 256);
    transpose_w_kernel<<<(1024 * 512 + 255) / 256, 256, 0, stream>>>(tw0, wtt0, 506, 1024, 512);
    transpose_w_kernel<<<(1024 * 1024 + 255) / 256, 256, 0, stream>>>(tw1, wtt1, 1024, 1024, 1024);
    transpose_w_kernel<<<(512 * 1024 + 255) / 256, 256, 0, stream>>>(tw2, wtt2, 1024, 512, 1024);
    transpose_w_kernel<<<(256 * 512 + 255) / 256, 256, 0, stream>>>(tw3, wtt3, 512, 256, 512);

    // bottom MLP
    bot0_kernel<<<BATCH / 8, 256, 0, stream>>>(dense, bw0, bb0, bufA);               // h0 -> A (512)
    gemm_kernel<<<dim3(BATCH / 128, 2), 256, 0, stream>>>(bufA, wtb1, bb1, bufB,
                                                          BATCH, 256, 512, 1);       // h1 -> B
    gemm_kernel<<<dim3(BATCH / 128, 1), 256, 0, stream>>>(bufB, wtb2, bb2, bufA,
                                                          BATCH, 128, 256, 1);       // bot -> A

    // interaction -> top_in (B, width 512)
    interact_kernel<<<BATCH / 4, 256, 0, stream>>>(cat, emb, bufA, bufB);

    // top MLP
    gemm_kernel<<<dim3(BATCH / 128, 8), 256, 0, stream>>>(bufB, wtt0, tb0, bufA,
                                                          BATCH, 1024, 512, 1);      // t0 -> A
    gemm_kernel<<<dim3(BATCH / 128, 8), 256, 0, stream>>>(bufA, wtt1, tb1, bufB,
                                                          BATCH, 1024, 1024, 1);     // t1 -> B
    gemm_kernel<<<dim3(BATCH / 128, 4), 256, 0, stream>>>(bufB, wtt2, tb2, bufA,
                                                          BATCH, 512, 1024, 1);      // t2 -> A
    gemm_kernel<<<dim3(BATCH / 128, 2), 256, 0, stream>>>(bufA, wtt3, tb3, bufB,
                                                          BATCH, 256, 512, 1);       // t3 -> B
    out_kernel<<<BATCH / 4, 256, 0, stream>>>(bufB, tw4, tb4, out);
}